// Round 1
// baseline (1135.436 us; speedup 1.0000x reference)
//
#include <hip/hip_runtime.h>
#include <math.h>

// One wave (64 lanes) per batch element; 4 elements per 256-thread block.
// Memory-bound problem: ~19.5 KB of per-element weights vs ~9.5 KFLOP.
#define WPB 4

__global__ __launch_bounds__(256) void batch_ode_kernel(
    const float* __restrict__ state,      // (B, 6)
    const float* __restrict__ tptr,       // (1,)
    const float* __restrict__ w1,         // (B, 64, 7)
    const float* __restrict__ b1,         // (B, 64)
    const float* __restrict__ w2,         // (B, 64, 64)
    const float* __restrict__ b2,         // (B, 64)
    const float* __restrict__ w3,         // (B, 3, 64)
    const float* __restrict__ b3,         // (B, 3)
    const float* __restrict__ log_omega,  // (B, 3)
    const float* __restrict__ log_gamma,  // (B, 3)
    float* __restrict__ out,              // (B, 6)
    int B)
{
    __shared__ __align__(16) float h1s[WPB][64];

    const int wave = threadIdx.x >> 6;
    const int lane = threadIdx.x & 63;
    const int b    = blockIdx.x * WPB + wave;
    const bool active = (b < B);

    const float* sp = state + (size_t)b * 6;

    if (active) {
        // x = [state(6), t]
        float x[7];
        #pragma unroll
        for (int j = 0; j < 6; ++j) x[j] = sp[j];   // same addr all lanes -> broadcast
        x[6] = tptr[0];

        // layer 1: lane i computes h1[i] = tanh(w1[b,i,:] . x + b1[b,i])
        const float* w1p = w1 + (size_t)b * 448 + lane * 7;
        float acc = b1[(size_t)b * 64 + lane];
        #pragma unroll
        for (int j = 0; j < 7; ++j) acc = fmaf(w1p[j], x[j], acc);
        h1s[wave][lane] = tanhf(acc);
    }
    __syncthreads();
    if (!active) return;

    // layer 2: lane i computes h2[i] = tanh(w2[b,i,:] . h1 + b2[b,i])
    // w2 row is 256B contiguous per lane -> 16x float4; h1 broadcast from LDS.
    const float4* w2p = (const float4*)(w2 + (size_t)b * 4096 + (size_t)lane * 64);
    const float4* h1v = (const float4*)(&h1s[wave][0]);
    float acc2 = b2[(size_t)b * 64 + lane];
    #pragma unroll
    for (int j = 0; j < 16; ++j) {
        float4 wv = w2p[j];
        float4 hv = h1v[j];
        acc2 = fmaf(wv.x, hv.x, acc2);
        acc2 = fmaf(wv.y, hv.y, acc2);
        acc2 = fmaf(wv.z, hv.z, acc2);
        acc2 = fmaf(wv.w, hv.w, acc2);
    }
    const float h2 = tanhf(acc2);

    // layer 3: corr[k] = w3[b,k,:] . h2 + b3[b,k], via butterfly reduce
    float corr[3];
    const float* w3p = w3 + (size_t)b * 192;
    const float* b3p = b3 + (size_t)b * 3;
    #pragma unroll
    for (int k = 0; k < 3; ++k) {
        float p = w3p[k * 64 + lane] * h2;
        #pragma unroll
        for (int off = 32; off > 0; off >>= 1)
            p += __shfl_xor(p, off, 64);
        corr[k] = p + b3p[k];   // b3 broadcast load, L1-hot
    }

    // epilogue: lanes 0..5 write [dz0, dv0, dz1, dv1, dz2, dv2]
    if (lane < 6) {
        const int k = lane >> 1;
        const float zk = sp[2 * k];       // L1-hot reload, avoids scratch-indexed x[]
        const float vk = sp[2 * k + 1];
        float o;
        if ((lane & 1) == 0) {
            o = vk;                        // dz = v
        } else {
            const float om = expf(log_omega[(size_t)b * 3 + k]);
            const float ga = expf(log_gamma[(size_t)b * 3 + k]);
            o = corr[k] - 2.0f * ga * vk - om * om * zk;   // dv
        }
        out[(size_t)b * 6 + lane] = o;
    }
}

extern "C" void kernel_launch(void* const* d_in, const int* in_sizes, int n_in,
                              void* d_out, int out_size, void* d_ws, size_t ws_size,
                              hipStream_t stream) {
    const float* state     = (const float*)d_in[0];
    const float* t         = (const float*)d_in[1];
    const float* w1        = (const float*)d_in[2];
    const float* b1        = (const float*)d_in[3];
    const float* w2        = (const float*)d_in[4];
    const float* b2        = (const float*)d_in[5];
    const float* w3        = (const float*)d_in[6];
    const float* b3        = (const float*)d_in[7];
    const float* log_omega = (const float*)d_in[8];
    const float* log_gamma = (const float*)d_in[9];
    float* out = (float*)d_out;

    const int B = in_sizes[0] / 6;
    const int grid = (B + WPB - 1) / WPB;
    batch_ode_kernel<<<grid, 256, 0, stream>>>(
        state, t, w1, b1, w2, b2, w3, b3, log_omega, log_gamma, out, B);
}

// Round 2
// 1103.377 us; speedup vs baseline: 1.0291x; 1.0291x over previous
//
#include <hip/hip_runtime.h>
#include <math.h>

// One wave (64 lanes) per batch element; 4 elements per 256-thread block.
// Memory-bound: ~19.5 KB of per-element weights vs ~9.5 KFLOP.
// Layer-2 matvec done as 16 groups of 4 rows: each group is one fully
// coalesced 1KB float4 load + subgroup-16 butterfly reduction.
#define WPB 4

__global__ __launch_bounds__(256) void batch_ode_kernel(
    const float* __restrict__ state,      // (B, 6)
    const float* __restrict__ tptr,       // (1,)
    const float* __restrict__ w1,         // (B, 64, 7)
    const float* __restrict__ b1,         // (B, 64)
    const float* __restrict__ w2,         // (B, 64, 64)
    const float* __restrict__ b2,         // (B, 64)
    const float* __restrict__ w3,         // (B, 3, 64)
    const float* __restrict__ b3,         // (B, 3)
    const float* __restrict__ log_omega,  // (B, 3)
    const float* __restrict__ log_gamma,  // (B, 3)
    float* __restrict__ out,              // (B, 6)
    int B)
{
    __shared__ __align__(16) float h1s[WPB][64];

    const int wave = threadIdx.x >> 6;
    const int lane = threadIdx.x & 63;
    const int b    = blockIdx.x * WPB + wave;
    const bool active = (b < B);

    const float* sp = state + (size_t)b * 6;

    if (active) {
        // x = [state(6), t]  (same-address loads -> broadcast, 1 line)
        float x[7];
        #pragma unroll
        for (int j = 0; j < 6; ++j) x[j] = sp[j];
        x[6] = tptr[0];

        // layer 1: lane i computes h1[i] = tanh(w1[b,i,:] . x + b1[b,i])
        const float* w1p = w1 + (size_t)b * 448 + lane * 7;
        float acc = b1[(size_t)b * 64 + lane];
        #pragma unroll
        for (int j = 0; j < 7; ++j) acc = fmaf(w1p[j], x[j], acc);
        h1s[wave][lane] = tanhf(acc);
    }
    __syncthreads();
    if (!active) return;

    // layer 2: h2[i] = tanh(w2[b,i,:] . h1 + b2[b,i])
    // group g covers rows 4g..4g+3; flat float4 idx = 64g + lane
    //   -> row = 4g + (lane>>4), col4 = lane&15. Fully coalesced.
    const int m   = lane & 15;       // column chunk (4 floats)
    const int q16 = (lane & 3) << 4; // source lane for my row's subgroup sum
    const int myg = lane >> 2;       // the group in which row==lane is computed

    const float4 hv = *(const float4*)&h1s[wave][4 * m];

    // prefetch all 16 coalesced 1KB slabs (independent loads, hide latency)
    const float4* w2v = (const float4*)w2 + (size_t)b * 1024 + lane;
    float4 wv[16];
    #pragma unroll
    for (int g = 0; g < 16; ++g) wv[g] = w2v[(size_t)g * 64];

    float acc2 = b2[(size_t)b * 64 + lane];
    #pragma unroll
    for (int g = 0; g < 16; ++g) {
        float p = wv[g].x * hv.x;
        p = fmaf(wv[g].y, hv.y, p);
        p = fmaf(wv[g].z, hv.z, p);
        p = fmaf(wv[g].w, hv.w, p);
        // reduce across the 16-lane subgroup (rows live on lane groups of 16)
        p += __shfl_xor(p, 1, 64);
        p += __shfl_xor(p, 2, 64);
        p += __shfl_xor(p, 4, 64);
        p += __shfl_xor(p, 8, 64);
        // route row (4g+q)'s dot to lane (4g+q): pull from subgroup (lane&3)
        const float got = __shfl(p, q16, 64);
        acc2 += (myg == g) ? got : 0.0f;
    }
    const float h2 = tanhf(acc2);

    // layer 3: corr[k] = w3[b,k,:] . h2 + b3[b,k] (coalesced + butterfly)
    float corr[3];
    const float* w3p = w3 + (size_t)b * 192;
    const float* b3p = b3 + (size_t)b * 3;
    #pragma unroll
    for (int k = 0; k < 3; ++k) {
        float p = w3p[k * 64 + lane] * h2;
        #pragma unroll
        for (int off = 32; off > 0; off >>= 1)
            p += __shfl_xor(p, off, 64);
        corr[k] = p + b3p[k];
    }

    // epilogue: lanes 0..5 write [dz0, dv0, dz1, dv1, dz2, dv2]
    if (lane < 6) {
        const int k = lane >> 1;
        const float zk = sp[2 * k];
        const float vk = sp[2 * k + 1];
        float o;
        if ((lane & 1) == 0) {
            o = vk;                        // dz = v
        } else {
            const float om = expf(log_omega[(size_t)b * 3 + k]);
            const float ga = expf(log_gamma[(size_t)b * 3 + k]);
            o = corr[k] - 2.0f * ga * vk - om * om * zk;   // dv
        }
        out[(size_t)b * 6 + lane] = o;
    }
}

extern "C" void kernel_launch(void* const* d_in, const int* in_sizes, int n_in,
                              void* d_out, int out_size, void* d_ws, size_t ws_size,
                              hipStream_t stream) {
    const float* state     = (const float*)d_in[0];
    const float* t         = (const float*)d_in[1];
    const float* w1        = (const float*)d_in[2];
    const float* b1        = (const float*)d_in[3];
    const float* w2        = (const float*)d_in[4];
    const float* b2        = (const float*)d_in[5];
    const float* w3        = (const float*)d_in[6];
    const float* b3        = (const float*)d_in[7];
    const float* log_omega = (const float*)d_in[8];
    const float* log_gamma = (const float*)d_in[9];
    float* out = (float*)d_out;

    const int B = in_sizes[0] / 6;
    const int grid = (B + WPB - 1) / WPB;
    batch_ode_kernel<<<grid, 256, 0, stream>>>(
        state, t, w1, b1, w2, b2, w3, b3, log_omega, log_gamma, out, B);
}